// Round 14
// baseline (335.418 us; speedup 1.0000x reference)
//
#include <hip/hip_runtime.h>
#include <hip/hip_bf16.h>

#define NN 20000
#define EE 320000
#define HD 128   // hidden

typedef _Float16 half8 __attribute__((ext_vector_type(8)));
typedef _Float16 half4 __attribute__((ext_vector_type(4)));
typedef _Float16 half2v __attribute__((ext_vector_type(2)));
typedef float floatx4 __attribute__((ext_vector_type(4)));
typedef float float2v __attribute__((ext_vector_type(2)));

// silu via HW rcp (1-ulp) instead of exact fp32 divide.
__device__ __forceinline__ float silu_f(float x){
  float e = __expf(-x);
  return x * __builtin_amdgcn_rcpf(1.f + e);
}

__device__ __forceinline__ bool ei_is64(const int* __restrict__ ei){
  return (ei[1] | ei[3] | ei[5] | ei[7]) == 0;
}
__device__ __forceinline__ int ei_src(const int* __restrict__ ei, int e, bool is64){
  return is64 ? ei[2*(size_t)e] : ei[e];
}
__device__ __forceinline__ int ei_dst(const int* __restrict__ ei, int e, bool is64){
  return is64 ? ei[2*(size_t)EE + 2*(size_t)e] : ei[EE + e];
}

__global__ __launch_bounds__(256) void sentinel_kernel(float* __restrict__ out, int n, float val){
  int i = blockIdx.x*256 + threadIdx.x;
  if (i < n) out[i] = val;
}

// ---------------- merged weight packing + cur zeroing (r9 — kept) ----------------
__global__ __launch_bounds__(256) void pack_all_kernel(const float* __restrict__ cw1,
                                                       const float* __restrict__ cw2,
                                                       const float* __restrict__ dw1,
                                                       const float* __restrict__ dw2,
                                                       _Float16* __restrict__ w1p,
                                                       _Float16* __restrict__ w2p,
                                                       _Float16* __restrict__ w1dp,
                                                       _Float16* __restrict__ w2dp,
                                                       int* __restrict__ cur){
  int idx = blockIdx.x*256 + threadIdx.x;
  if (idx >= 319488){
    int j = idx - 319488;
    if (j < NN) cur[j] = 0;
    return;
  }
  if (idx < 196608){
    int j   = idx & 7;
    int ln  = (idx >> 3) & 63;
    int rest= idx >> 9;
    int cb  = rest & 15;
    int rest2 = rest >> 4;
    int ks  = rest2 & 3;
    int l   = rest2 >> 2;
    int k = ks*32 + (ln>>4)*8 + j;
    int c = cb*16 + (ln&15);
    float v = (c < 128) ? cw1[(size_t)l*33152 + (size_t)k*128 + c]
                        : cw1[(size_t)l*33152 + (size_t)(128+k)*128 + (c-128)];
    w1p[idx] = (_Float16)v;
  } else if (idx < 294912){
    int t = idx - 196608;
    int j   = t & 7;
    int ln  = (t >> 3) & 63;
    int rest= t >> 9;
    int cb  = rest & 7;
    int rest2 = rest >> 3;
    int ks  = rest2 & 3;
    int l   = rest2 >> 2;
    int k = ks*32 + (ln>>4)*8 + j;
    int c = cb*16 + (ln&15);
    w2p[t] = (_Float16)cw2[(size_t)l*16384 + (size_t)k*128 + c];
  } else {
    int t2 = idx - 294912;
    if (t2 < 16384){
      int j = t2 & 7, ln = (t2>>3)&63, cb = (t2>>9)&7, ks = t2>>12;
      int k = ks*32 + (ln>>4)*8 + j;
      int c = cb*16 + (ln&15);
      w1dp[t2] = (_Float16)dw1[(size_t)k*128 + c];
    } else {
      int t = t2 - 16384;
      int j = t & 7, ln = (t>>3)&63, cb = (t>>9)&3, ks = t>>11;
      int k = ks*32 + (ln>>4)*8 + j;
      int c = cb*16 + (ln&15);
      w2dp[t] = (_Float16)dw2[(size_t)k*64 + c];
    }
  }
}

// ---------------- CSR build (r12 structure + r14 degree-sort) ----------------
__global__ __launch_bounds__(256) void count_kernel(const int* __restrict__ ei,
                                                    int* __restrict__ cnt,
                                                    int* __restrict__ rank){
  int e = blockIdx.x*256 + threadIdx.x;   // EE/256 exact
  bool is64 = ei_is64(ei);
  rank[e] = atomicAdd(&cnt[ei_dst(ei, e, is64)], 1);
}

// r14: also emits perm = nodes counting-sorted by degree DESCENDING. Blocks of
// 16 consecutive perm entries then have near-equal degree (kills the fused
// layer's barrier tail: block max-deg ~= block mean-deg), and heavy blocks
// schedule first (LPT -> minimal makespan). Bin order within a degree is
// nondeterministic but per-node math is untouched -> bitwise-identical output.
__global__ __launch_bounds__(1024) void scan_kernel(const int* __restrict__ cntcur,
                                                    int* __restrict__ row_start,
                                                    float* __restrict__ invd,
                                                    int* __restrict__ perm){
  __shared__ int part[1024];
  __shared__ int hist[256];
  const int t = threadIdx.x;
  const int base = t*20;
  int loc[20];
  int truedeg[20];
  int sum = 0;
  #pragma unroll
  for (int i=0;i<20;++i){
    int n = base+i;
    int v = (n < NN) ? cntcur[n] : 0;
    truedeg[i] = v;
    loc[i] = sum; sum += v;
  }
  part[t] = sum;
  __syncthreads();
  for (int off=1; off<1024; off<<=1){
    int v = (t >= off) ? part[t-off] : 0;
    __syncthreads();
    part[t] += v;
    __syncthreads();
  }
  int pre = (t > 0) ? part[t-1] : 0;
  #pragma unroll
  for (int i=0;i<20;++i){
    int n = base+i;
    if (n < NN){
      row_start[n] = pre + loc[i];
      invd[n] = (truedeg[i] > 0) ? 1.f/(float)truedeg[i] : 0.f;
    }
  }
  if (t == 1023) row_start[NN] = part[1023];

  // ---- degree counting-sort (descending) -> perm ----
  if (t < 256) hist[t] = 0;
  __syncthreads();
  #pragma unroll
  for (int i=0;i<20;++i){
    int n = base+i;
    if (n < NN){
      int b = 255 - (truedeg[i] < 255 ? truedeg[i] : 255);  // descending
      atomicAdd(&hist[b], 1);
    }
  }
  __syncthreads();
  if (t == 0){
    int s = 0;
    for (int b=0;b<256;++b){ int v = hist[b]; hist[b] = s; s += v; }
  }
  __syncthreads();
  #pragma unroll
  for (int i=0;i<20;++i){
    int n = base+i;
    if (n < NN){
      int b = 255 - (truedeg[i] < 255 ? truedeg[i] : 255);
      int pos = atomicAdd(&hist[b], 1);
      perm[pos] = n;
    }
  }
}

// ---------------- scatter + encoder merged (r12 exact) ----------------
__global__ __launch_bounds__(128) void scatter_encoder_kernel(
    const int* __restrict__ ei, const float* __restrict__ eattr,
    const int* __restrict__ rstart, const int* __restrict__ rank,
    int4* __restrict__ rec,
    const float* __restrict__ x, const float* __restrict__ w1, const float* __restrict__ b1,
    const float* __restrict__ w2, const float* __restrict__ b2,
    float* __restrict__ h, _Float16* __restrict__ hh)
{
  __shared__ float xs[16][14];
  __shared__ float s1[16][128];
  const int tid = threadIdx.x;

  if (blockIdx.x < 2500){
    int e = blockIdx.x*128 + tid;       // 2500*128 = 320000 exact
    bool is64 = ei_is64(ei);
    int s = ei_src(ei, e, is64);
    int d = ei_dst(ei, e, is64);
    int pos = rstart[d] + rank[e];
    int4 r;
    r.x = __float_as_int(eattr[(size_t)e*3+0]);
    r.y = __float_as_int(eattr[(size_t)e*3+1]);
    r.z = __float_as_int(eattr[(size_t)e*3+2]);
    r.w = s*256;   // pre-scaled UV row element-offset
    rec[pos] = r;
    return;
  }

  const int n0 = (blockIdx.x - 2500)*16;
  for (int idx=tid; idx<224; idx+=128){
    int i = idx/14, k = idx%14;
    xs[i][k] = x[(size_t)(n0+i)*14 + k];
  }
  __syncthreads();
  const int o = tid;
  float acc[16];
  float bv = b1[o];
  #pragma unroll
  for (int i=0;i<16;++i) acc[i] = bv;
  for (int k=0;k<14;++k){
    float w = w1[k*128+o];
    #pragma unroll
    for (int i=0;i<16;++i) acc[i] += xs[i][k]*w;
  }
  #pragma unroll
  for (int i=0;i<16;++i) s1[i][o] = silu_f(acc[i]);
  __syncthreads();
  float bv2 = b2[o];
  #pragma unroll
  for (int i=0;i<16;++i) acc[i] = bv2;
  for (int k=0;k<128;k+=4){
    float w0=w2[(k+0)*128+o], w1v=w2[(k+1)*128+o], w2v=w2[(k+2)*128+o], w3v=w2[(k+3)*128+o];
    #pragma unroll
    for (int i=0;i<16;++i){
      float4 sv = *(const float4*)&s1[i][k];
      acc[i] += sv.x*w0 + sv.y*w1v + sv.z*w2v + sv.w*w3v;
    }
  }
  #pragma unroll
  for (int i=0;i<16;++i){
    size_t off = (size_t)(n0+i)*HD + o;
    h[off] = acc[i];
    hh[off] = (_Float16)acc[i];
  }
}

// ---------------- proj (r4 exact): layer-0 UV from hh (unpermuted) ----------------
__global__ __launch_bounds__(256) void proj_kernel(
    const _Float16* __restrict__ hh, const _Float16* __restrict__ w1p,
    const float* __restrict__ b1, _Float16* __restrict__ UV)
{
  const int tid = threadIdx.x;
  const int wv  = tid >> 6;
  const int ln  = tid & 63;
  const int q   = ln >> 4;
  const int m   = ln & 15;
  const int n0  = blockIdx.x*16;      // grid = NN/16 = 1250 exact

  floatx4 acc[4];
  #pragma unroll
  for (int j=0;j<4;++j) acc[j] = (floatx4){0.f,0.f,0.f,0.f};

  #pragma unroll
  for (int ks=0; ks<4; ++ks){
    half8 a = *(const half8*)(hh + (size_t)(n0+m)*HD + ks*32 + q*8);
    const _Float16* wb = w1p + (size_t)(ks*16*64 + ln)*8;
    #pragma unroll
    for (int j=0; j<4; ++j){
      half8 b = *(const half8*)(wb + (size_t)(wv*4+j)*512);
      acc[j] = __builtin_amdgcn_mfma_f32_16x16x32_f16(a, b, acc[j], 0,0,0);
    }
  }
  #pragma unroll
  for (int j=0; j<4; ++j){
    const int c = (wv*4+j)*16 + m;
    const float bias = (c < 128) ? b1[c] : 0.f;
    #pragma unroll
    for (int r=0;r<4;++r)
      UV[(size_t)(n0+q*4+r)*256 + c] = (_Float16)(acc[j][r] + bias);
  }
}

// ---------------- fused layer (r13 + r14 perm): 1024 thr = 16 waves = 16 nodes ----------------
__device__ __forceinline__ float2v edge_contrib(int4 r, half2v v, float2v u,
                                                float2v wc0, float2v wc1, float2v wc2){
  float2v p = u;
  p += __int_as_float(r.x) * wc0;
  p += __int_as_float(r.y) * wc1;
  p += __int_as_float(r.z) * wc2;
  p[0] += (float)v[0];
  p[1] += (float)v[1];
  float2v s;
  s[0] = silu_f(p[0]);
  s[1] = silu_f(p[1]);
  return s;
}

__global__ __launch_bounds__(1024, 8) void layer_kernel(
    const _Float16* __restrict__ UVc, _Float16* __restrict__ UVn,
    const int* __restrict__ row_start, const int4* __restrict__ rec,
    const float* __restrict__ w1e, const float* __restrict__ invd,
    const int* __restrict__ perm,
    const _Float16* __restrict__ w2p, const float* __restrict__ b2,
    float* __restrict__ h,
    const _Float16* __restrict__ w1pn, const float* __restrict__ b1n,
    int do_proj,
    const _Float16* __restrict__ w1dp, const float* __restrict__ db1,
    const _Float16* __restrict__ w2dp, const float* __restrict__ db2,
    const float* __restrict__ dw3, const float* __restrict__ db3,
    float* __restrict__ out, int do_dec)
{
  __shared__ _Float16 Sl[16][136];
  __shared__ _Float16 hl[16][136];
  __shared__ int pnode[16];
  __shared__ __align__(16) char ubuf[8576];           // dl | (d1 + s2m)
  float    (*dl)[132]  = (float(*)[132])ubuf;         // 16*132*4 = 8448
  _Float16 (*d1)[136]  = (_Float16(*)[136])ubuf;      // 16*136*2 = 4352
  float    (*s2m)[66]  = (float(*)[66])(ubuf + 4352); // 16*66*4  = 4224

  const int tid = threadIdx.x;
  const int w   = __builtin_amdgcn_readfirstlane(tid >> 6);   // wave 0..15
  const int ln  = tid & 63;
  const int q   = ln >> 4;
  const int m   = ln & 15;
  const int n0  = blockIdx.x*16;      // grid = NN/16 = 1250 exact

  // ---- phase 0: edge aggregation, 1 node per wave (permuted node id) ----
  {
    const int n  = perm[n0 + w];      // wave-uniform -> scalar load
    if (ln == 0) pnode[w] = n;        // published by the phase-0 barrier
    const int c0 = ln*2;
    const float2v wc0 = *(const float2v*)(w1e +   0 + c0);
    const float2v wc1 = *(const float2v*)(w1e + 128 + c0);
    const float2v wc2 = *(const float2v*)(w1e + 256 + c0);

    half2v uvp = *(const half2v*)(UVc + (size_t)n*256 + c0);
    float2v u; u[0] = (float)uvp[0]; u[1] = (float)uvp[1];

    const int rs = row_start[n], re = row_start[n+1];
    float2v a0 = {0.f,0.f}, a1 = {0.f,0.f}, a2 = {0.f,0.f}, a3 = {0.f,0.f};

    const int nq = (re - rs) >> 2;
    int e = rs;
    for (int qq = 0; qq < nq; ++qq, e += 4){
      const int4 r0 = rec[e+0];
      const int4 r1 = rec[e+1];
      const int4 r2 = rec[e+2];
      const int4 r3 = rec[e+3];
      const half2v v0 = *(const half2v*)(UVc + (size_t)r0.w + 128 + c0);
      const half2v v1 = *(const half2v*)(UVc + (size_t)r1.w + 128 + c0);
      const half2v v2 = *(const half2v*)(UVc + (size_t)r2.w + 128 + c0);
      const half2v v3 = *(const half2v*)(UVc + (size_t)r3.w + 128 + c0);
      a0 += edge_contrib(r0, v0, u, wc0, wc1, wc2);
      a1 += edge_contrib(r1, v1, u, wc0, wc1, wc2);
      a2 += edge_contrib(r2, v2, u, wc0, wc1, wc2);
      a3 += edge_contrib(r3, v3, u, wc0, wc1, wc2);
    }
    if (e < re){
      const int e1 = (e+1 < re) ? e+1 : e;
      const int e2 = (e+2 < re) ? e+2 : e;
      const int4 r0 = rec[e];
      const int4 r1 = rec[e1];
      const int4 r2 = rec[e2];
      const half2v v0 = *(const half2v*)(UVc + (size_t)r0.w + 128 + c0);
      const half2v v1 = *(const half2v*)(UVc + (size_t)r1.w + 128 + c0);
      const half2v v2 = *(const half2v*)(UVc + (size_t)r2.w + 128 + c0);
      a0 += edge_contrib(r0, v0, u, wc0, wc1, wc2);
      if (e+1 < re) a1 += edge_contrib(r1, v1, u, wc0, wc1, wc2);
      if (e+2 < re) a2 += edge_contrib(r2, v2, u, wc0, wc1, wc2);
    }
    float2v a = (a0 + a1) + (a2 + a3);
    const float iv = invd[n];
    half2v outv; outv[0] = (_Float16)(a[0]*iv); outv[1] = (_Float16)(a[1]*iv);
    *(half2v*)&Sl[w][c0] = outv;
  }
  __syncthreads();

  // ---- phase 1: S·W2 -> dl (waves 0-7, one 16x16 col-block each) ----
  if (w < 8){
    floatx4 acc = (floatx4){0.f,0.f,0.f,0.f};
    #pragma unroll
    for (int ks=0; ks<4; ++ks){
      half8 a = *(const half8*)&Sl[m][ks*32 + q*8];
      half8 b = *(const half8*)(w2p + (size_t)(ks*8*64 + ln)*8 + (size_t)w*512);
      acc = __builtin_amdgcn_mfma_f32_16x16x32_f16(a, b, acc, 0,0,0);
    }
    const int c = w*16 + m;
    #pragma unroll
    for (int r=0;r<4;++r) dl[q*4+r][c] = acc[r];
  }
  __syncthreads();

  // ---- phase 2: coalesced h RMW (2 ch/thread); hl fp16 ----
  {
    const int row = w;                  // 2048 elems / 1024 thr = 2 each
    const int pn  = pnode[row];
    const int col = ln*2;
    const float g = (invd[pn] > 0.f) ? 1.f : 0.f;
    float2 hv = *(const float2*)&h[(size_t)pn*HD + col];
    float2 bv = *(const float2*)&b2[col];
    float2 dv = *(const float2*)&dl[row][col];
    hv.x += dv.x + g*bv.x;
    hv.y += dv.y + g*bv.y;
    if (!do_dec)
      *(float2*)&h[(size_t)pn*HD + col] = hv;
    half2v p; p[0] = (_Float16)hv.x; p[1] = (_Float16)hv.y;
    *(half2v*)&hl[row][col] = p;
  }
  __syncthreads();

  // ---- phase 3a: fused proj(l+1) (16 waves, one col-block each) ----
  if (do_proj){
    floatx4 acc = (floatx4){0.f,0.f,0.f,0.f};
    #pragma unroll
    for (int ks=0; ks<4; ++ks){
      half8 a = *(const half8*)&hl[m][ks*32 + q*8];
      half8 b = *(const half8*)(w1pn + (size_t)(ks*16*64 + ln)*8 + (size_t)w*512);
      acc = __builtin_amdgcn_mfma_f32_16x16x32_f16(a, b, acc, 0,0,0);
    }
    const int c = w*16 + m;
    const float bias = (c < 128) ? b1n[c] : 0.f;
    #pragma unroll
    for (int r=0;r<4;++r)
      UVn[(size_t)pnode[q*4+r]*256 + c] = (_Float16)(acc[r] + bias);
  }

  // ---- phase 3b: fused decoder (l==5) ----
  if (do_dec){
    if (w < 8){
      floatx4 acc = (floatx4){0.f,0.f,0.f,0.f};
      #pragma unroll
      for (int ks=0; ks<4; ++ks){
        half8 a = *(const half8*)&hl[m][ks*32 + q*8];
        half8 b = *(const half8*)(w1dp + (size_t)(ks*8*64 + ln)*8 + (size_t)w*512);
        acc = __builtin_amdgcn_mfma_f32_16x16x32_f16(a, b, acc, 0,0,0);
      }
      const int c = w*16 + m;
      const float bv = db1[c];
      #pragma unroll
      for (int r=0;r<4;++r)
        d1[q*4+r][c] = (_Float16)silu_f(acc[r] + bv);
    }
    __syncthreads();

    if (w < 4){
      floatx4 acc = (floatx4){0.f,0.f,0.f,0.f};
      #pragma unroll
      for (int ks=0; ks<4; ++ks){
        half8 a = *(const half8*)&d1[m][ks*32 + q*8];
        half8 b = *(const half8*)(w2dp + (size_t)(ks*4*64 + ln)*8 + (size_t)w*512);
        acc = __builtin_amdgcn_mfma_f32_16x16x32_f16(a, b, acc, 0,0,0);
      }
      const int c = w*16 + m;
      const float bv = db2[c];
      #pragma unroll
      for (int r=0;r<4;++r)
        s2m[q*4+r][c] = silu_f(acc[r] + bv);
    }
    __syncthreads();

    if (tid < 144){
      int i = tid/9, oo = tid%9;
      float a = db3[oo];
      #pragma unroll 8
      for (int k=0;k<64;++k) a += s2m[i][k]*dw3[k*9+oo];
      out[(size_t)pnode[i]*9 + oo] = a;
    }
  }
}

// ---------------- workspace layout (43,199,040 B) ----------------
constexpr size_t OFF_H    = 0;                         // 10,240,000
constexpr size_t OFF_HH   = 10240000;                  //  5,120,000
constexpr size_t OFF_UVA  = 15360000;                  // 10,240,000
constexpr size_t OFF_UVB  = 25600000;                  // 10,240,000
constexpr size_t OFF_INVD = 35840000;                  //     80,000
constexpr size_t OFF_RS   = 35920000;                  //     80,064
constexpr size_t OFF_CUR  = 36000064;                  //     80,000
constexpr size_t OFF_REC  = 36080064;                  //  5,120,000 (int4/edge)
constexpr size_t OFF_RANK = 41200064;                  //  1,280,000 (int/edge)
constexpr size_t OFF_PERM = 42480064;                  //     80,000
constexpr size_t OFF_W1P  = 42560064;                  //    393,216
constexpr size_t OFF_W2P  = 42953280;                  //    196,608
constexpr size_t OFF_DW1P = 43149888;                  //     32,768
constexpr size_t OFF_DW2P = 43182656;                  //     16,384
constexpr size_t WS_NEEDED= 43199040;

extern "C" void kernel_launch(void* const* d_in, const int* in_sizes, int n_in,
                              void* d_out, int out_size, void* d_ws, size_t ws_size,
                              hipStream_t stream)
{
  float* out = (float*)d_out;
  const int nout_blk = (out_size + 255)/256;

  static const int EXP_SIZES[17] = {280000,640000,960000,1792,128,16384,128,
                                    198912,768,98304,768,16384,128,8192,64,576,9};
  if (n_in != 17){
    sentinel_kernel<<<nout_blk, 256, 0, stream>>>(out, out_size, 2.0e7f + (float)n_in*1.0e3f);
    return;
  }
  for (int i = 0; i < 17; ++i){
    if (in_sizes[i] != EXP_SIZES[i]){
      int sz = in_sizes[i] < 99999 ? in_sizes[i] : 99999;
      sentinel_kernel<<<nout_blk, 256, 0, stream>>>(out, out_size,
          1.0e7f + (float)i*1.0e5f + (float)sz);
      return;
    }
  }
  if (ws_size < WS_NEEDED){
    sentinel_kernel<<<nout_blk, 256, 0, stream>>>(out, out_size, 1.0e6f);
    return;
  }

  const float* x       = (const float*)d_in[0];
  const int*   ei      = (const int*)  d_in[1];
  const float* eattr   = (const float*)d_in[2];
  const float* enc_w1  = (const float*)d_in[3];
  const float* enc_b1  = (const float*)d_in[4];
  const float* enc_w2  = (const float*)d_in[5];
  const float* enc_b2  = (const float*)d_in[6];
  const float* conv_w1 = (const float*)d_in[7];
  const float* conv_b1 = (const float*)d_in[8];
  const float* conv_w2 = (const float*)d_in[9];
  const float* conv_b2 = (const float*)d_in[10];
  const float* dec_w1  = (const float*)d_in[11];
  const float* dec_b1  = (const float*)d_in[12];
  const float* dec_w2  = (const float*)d_in[13];
  const float* dec_b2  = (const float*)d_in[14];
  const float* dec_w3  = (const float*)d_in[15];
  const float* dec_b3  = (const float*)d_in[16];

  char* ws = (char*)d_ws;
  float*    h     = (float*)   (ws + OFF_H);
  _Float16* hh    = (_Float16*)(ws + OFF_HH);
  _Float16* UVa   = (_Float16*)(ws + OFF_UVA);
  _Float16* UVb   = (_Float16*)(ws + OFF_UVB);
  float*    invd  = (float*)   (ws + OFF_INVD);
  int*      rstart= (int*)     (ws + OFF_RS);
  int*      cur   = (int*)     (ws + OFF_CUR);
  int4*     rec   = (int4*)    (ws + OFF_REC);
  int*      rank  = (int*)     (ws + OFF_RANK);
  int*      perm  = (int*)     (ws + OFF_PERM);
  _Float16* w1p   = (_Float16*)(ws + OFF_W1P);
  _Float16* w2p   = (_Float16*)(ws + OFF_W2P);
  _Float16* w1dp  = (_Float16*)(ws + OFF_DW1P);
  _Float16* w2dp  = (_Float16*)(ws + OFF_DW2P);

  pack_all_kernel<<<1327, 256, 0, stream>>>(conv_w1, conv_w2, dec_w1, dec_w2,
                                            w1p, w2p, w1dp, w2dp, cur);
  count_kernel<<<EE/256, 256, 0, stream>>>(ei, cur, rank);
  scan_kernel<<<1, 1024, 0, stream>>>(cur, rstart, invd, perm);
  scatter_encoder_kernel<<<3750, 128, 0, stream>>>(ei, eattr, rstart, rank, rec,
                                                   x, enc_w1, enc_b1, enc_w2, enc_b2,
                                                   h, hh);
  proj_kernel<<<NN/16, 256, 0, stream>>>(hh, w1p, conv_b1, UVa);   // layer 0 proj
  for (int l=0; l<6; ++l){
    _Float16* UVc = (l & 1) ? UVb : UVa;
    _Float16* UVn = (l & 1) ? UVa : UVb;
    const int lp = (l < 5) ? l+1 : 0;   // dummy valid ptrs for last layer
    layer_kernel<<<NN/16, 1024, 0, stream>>>(UVc, UVn, rstart, rec,
                                             conv_w1 + (size_t)l*33152 + 32768,
                                             invd, perm,
                                             w2p + (size_t)l*16384,
                                             conv_b2 + (size_t)l*128,
                                             h,
                                             w1p + (size_t)lp*32768,
                                             conv_b1 + (size_t)lp*128,
                                             (l < 5) ? 1 : 0,
                                             w1dp, dec_b1, w2dp, dec_b2,
                                             dec_w3, dec_b3, out,
                                             (l == 5) ? 1 : 0);
  }
}

// Round 15
// 331.742 us; speedup vs baseline: 1.0111x; 1.0111x over previous
//
#include <hip/hip_runtime.h>
#include <hip/hip_bf16.h>

#define NN 20000
#define EE 320000
#define HD 128   // hidden

typedef _Float16 half8 __attribute__((ext_vector_type(8)));
typedef _Float16 half4 __attribute__((ext_vector_type(4)));
typedef _Float16 half2v __attribute__((ext_vector_type(2)));
typedef float floatx4 __attribute__((ext_vector_type(4)));
typedef float float2v __attribute__((ext_vector_type(2)));

// silu via HW rcp (1-ulp) instead of exact fp32 divide.
__device__ __forceinline__ float silu_f(float x){
  float e = __expf(-x);
  return x * __builtin_amdgcn_rcpf(1.f + e);
}

__device__ __forceinline__ bool ei_is64(const int* __restrict__ ei){
  return (ei[1] | ei[3] | ei[5] | ei[7]) == 0;
}
__device__ __forceinline__ int ei_src(const int* __restrict__ ei, int e, bool is64){
  return is64 ? ei[2*(size_t)e] : ei[e];
}
__device__ __forceinline__ int ei_dst(const int* __restrict__ ei, int e, bool is64){
  return is64 ? ei[2*(size_t)EE + 2*(size_t)e] : ei[EE + e];
}

__global__ __launch_bounds__(256) void sentinel_kernel(float* __restrict__ out, int n, float val){
  int i = blockIdx.x*256 + threadIdx.x;
  if (i < n) out[i] = val;
}

// ---------------- merged weight packing + cur zeroing ----------------
__global__ __launch_bounds__(256) void pack_all_kernel(const float* __restrict__ cw1,
                                                       const float* __restrict__ cw2,
                                                       const float* __restrict__ dw1,
                                                       const float* __restrict__ dw2,
                                                       _Float16* __restrict__ w1p,
                                                       _Float16* __restrict__ w2p,
                                                       _Float16* __restrict__ w1dp,
                                                       _Float16* __restrict__ w2dp,
                                                       int* __restrict__ cur){
  int idx = blockIdx.x*256 + threadIdx.x;
  if (idx >= 319488){
    int j = idx - 319488;
    if (j < NN) cur[j] = 0;
    return;
  }
  if (idx < 196608){
    int j   = idx & 7;
    int ln  = (idx >> 3) & 63;
    int rest= idx >> 9;
    int cb  = rest & 15;
    int rest2 = rest >> 4;
    int ks  = rest2 & 3;
    int l   = rest2 >> 2;
    int k = ks*32 + (ln>>4)*8 + j;
    int c = cb*16 + (ln&15);
    float v = (c < 128) ? cw1[(size_t)l*33152 + (size_t)k*128 + c]
                        : cw1[(size_t)l*33152 + (size_t)(128+k)*128 + (c-128)];
    w1p[idx] = (_Float16)v;
  } else if (idx < 294912){
    int t = idx - 196608;
    int j   = t & 7;
    int ln  = (t >> 3) & 63;
    int rest= t >> 9;
    int cb  = rest & 7;
    int rest2 = rest >> 3;
    int ks  = rest2 & 3;
    int l   = rest2 >> 2;
    int k = ks*32 + (ln>>4)*8 + j;
    int c = cb*16 + (ln&15);
    w2p[t] = (_Float16)cw2[(size_t)l*16384 + (size_t)k*128 + c];
  } else {
    int t2 = idx - 294912;
    if (t2 < 16384){
      int j = t2 & 7, ln = (t2>>3)&63, cb = (t2>>9)&7, ks = t2>>12;
      int k = ks*32 + (ln>>4)*8 + j;
      int c = cb*16 + (ln&15);
      w1dp[t2] = (_Float16)dw1[(size_t)k*128 + c];
    } else {
      int t = t2 - 16384;
      int j = t & 7, ln = (t>>3)&63, cb = (t>>9)&3, ks = t>>11;
      int k = ks*32 + (ln>>4)*8 + j;
      int c = cb*16 + (ln&15);
      w2dp[t] = (_Float16)dw2[(size_t)k*64 + c];
    }
  }
}

// ---------------- CSR build (r12 exact) ----------------
__global__ __launch_bounds__(256) void count_kernel(const int* __restrict__ ei,
                                                    int* __restrict__ cnt,
                                                    int* __restrict__ rank){
  int e = blockIdx.x*256 + threadIdx.x;   // EE/256 exact
  bool is64 = ei_is64(ei);
  rank[e] = atomicAdd(&cnt[ei_dst(ei, e, is64)], 1);
}

__global__ __launch_bounds__(1024) void scan_kernel(const int* __restrict__ cntcur,
                                                    int* __restrict__ row_start,
                                                    float* __restrict__ invd){
  __shared__ int part[1024];
  const int t = threadIdx.x;
  const int base = t*20;
  int loc[20];
  int sum = 0;
  #pragma unroll
  for (int i=0;i<20;++i){
    int n = base+i;
    int v = (n < NN) ? cntcur[n] : 0;
    loc[i] = sum; sum += v;
  }
  part[t] = sum;
  __syncthreads();
  for (int off=1; off<1024; off<<=1){
    int v = (t >= off) ? part[t-off] : 0;
    __syncthreads();
    part[t] += v;
    __syncthreads();
  }
  int pre = (t > 0) ? part[t-1] : 0;
  #pragma unroll
  for (int i=0;i<20;++i){
    int n = base+i;
    if (n < NN){
      int rs = pre + loc[i];
      int deg = ((i<19)?loc[i+1]:sum) - loc[i];
      row_start[n] = rs;
      invd[n] = (deg > 0) ? 1.f/(float)deg : 0.f;
    }
  }
  if (t == 1023) row_start[NN] = part[1023];
}

// ---------------- scatter + encoder merged (r12 exact) ----------------
__global__ __launch_bounds__(128) void scatter_encoder_kernel(
    const int* __restrict__ ei, const float* __restrict__ eattr,
    const int* __restrict__ rstart, const int* __restrict__ rank,
    int4* __restrict__ rec,
    const float* __restrict__ x, const float* __restrict__ w1, const float* __restrict__ b1,
    const float* __restrict__ w2, const float* __restrict__ b2,
    float* __restrict__ h, _Float16* __restrict__ hh)
{
  __shared__ float xs[16][14];
  __shared__ float s1[16][128];
  const int tid = threadIdx.x;

  if (blockIdx.x < 2500){
    int e = blockIdx.x*128 + tid;       // 2500*128 = 320000 exact
    bool is64 = ei_is64(ei);
    int s = ei_src(ei, e, is64);
    int d = ei_dst(ei, e, is64);
    int pos = rstart[d] + rank[e];
    int4 r;
    r.x = __float_as_int(eattr[(size_t)e*3+0]);
    r.y = __float_as_int(eattr[(size_t)e*3+1]);
    r.z = __float_as_int(eattr[(size_t)e*3+2]);
    r.w = s*256;   // pre-scaled UV row element-offset
    rec[pos] = r;
    return;
  }

  const int n0 = (blockIdx.x - 2500)*16;
  for (int idx=tid; idx<224; idx+=128){
    int i = idx/14, k = idx%14;
    xs[i][k] = x[(size_t)(n0+i)*14 + k];
  }
  __syncthreads();
  const int o = tid;
  float acc[16];
  float bv = b1[o];
  #pragma unroll
  for (int i=0;i<16;++i) acc[i] = bv;
  for (int k=0;k<14;++k){
    float w = w1[k*128+o];
    #pragma unroll
    for (int i=0;i<16;++i) acc[i] += xs[i][k]*w;
  }
  #pragma unroll
  for (int i=0;i<16;++i) s1[i][o] = silu_f(acc[i]);
  __syncthreads();
  float bv2 = b2[o];
  #pragma unroll
  for (int i=0;i<16;++i) acc[i] = bv2;
  for (int k=0;k<128;k+=4){
    float w0=w2[(k+0)*128+o], w1v=w2[(k+1)*128+o], w2v=w2[(k+2)*128+o], w3v=w2[(k+3)*128+o];
    #pragma unroll
    for (int i=0;i<16;++i){
      float4 sv = *(const float4*)&s1[i][k];
      acc[i] += sv.x*w0 + sv.y*w1v + sv.z*w2v + sv.w*w3v;
    }
  }
  #pragma unroll
  for (int i=0;i<16;++i){
    size_t off = (size_t)(n0+i)*HD + o;
    h[off] = acc[i];
    hh[off] = (_Float16)acc[i];
  }
}

// ---------------- proj (r4 exact): layer-0 UV from hh ----------------
__global__ __launch_bounds__(256) void proj_kernel(
    const _Float16* __restrict__ hh, const _Float16* __restrict__ w1p,
    const float* __restrict__ b1, _Float16* __restrict__ UV)
{
  const int tid = threadIdx.x;
  const int wv  = tid >> 6;
  const int ln  = tid & 63;
  const int q   = ln >> 4;
  const int m   = ln & 15;
  const int n0  = blockIdx.x*16;      // grid = NN/16 = 1250 exact

  floatx4 acc[4];
  #pragma unroll
  for (int j=0;j<4;++j) acc[j] = (floatx4){0.f,0.f,0.f,0.f};

  #pragma unroll
  for (int ks=0; ks<4; ++ks){
    half8 a = *(const half8*)(hh + (size_t)(n0+m)*HD + ks*32 + q*8);
    const _Float16* wb = w1p + (size_t)(ks*16*64 + ln)*8;
    #pragma unroll
    for (int j=0; j<4; ++j){
      half8 b = *(const half8*)(wb + (size_t)(wv*4+j)*512);
      acc[j] = __builtin_amdgcn_mfma_f32_16x16x32_f16(a, b, acc[j], 0,0,0);
    }
  }
  #pragma unroll
  for (int j=0; j<4; ++j){
    const int c = (wv*4+j)*16 + m;
    const float bias = (c < 128) ? b1[c] : 0.f;
    #pragma unroll
    for (int r=0;r<4;++r)
      UV[(size_t)(n0+q*4+r)*256 + c] = (_Float16)(acc[j][r] + bias);
  }
}

// ---------------- fused layer (r13): 1024 thr = 16 waves = 16 nodes ----------------
// Edge phase is r4's edge_agg VERBATIM per wave (1 node/wave). S lives in LDS
// (no 10MB/layer HBM round-trip). Node phases reuse the block's S/h: S·W2
// (waves 0-7, 1 cb each), coalesced h RMW, then proj(l+1) (16 waves, 1 cb
// each) or decoder (l==5). launch_bounds(1024,8) -> 2 blocks/CU -> 8 waves/SIMD.
// r14's degree-sort perm was NEUTRAL (within noise, locality offset) — reverted.
__device__ __forceinline__ float2v edge_contrib(int4 r, half2v v, float2v u,
                                                float2v wc0, float2v wc1, float2v wc2){
  float2v p = u;
  p += __int_as_float(r.x) * wc0;
  p += __int_as_float(r.y) * wc1;
  p += __int_as_float(r.z) * wc2;
  p[0] += (float)v[0];
  p[1] += (float)v[1];
  float2v s;
  s[0] = silu_f(p[0]);
  s[1] = silu_f(p[1]);
  return s;
}

__global__ __launch_bounds__(1024, 8) void layer_kernel(
    const _Float16* __restrict__ UVc, _Float16* __restrict__ UVn,
    const int* __restrict__ row_start, const int4* __restrict__ rec,
    const float* __restrict__ w1e, const float* __restrict__ invd,
    const _Float16* __restrict__ w2p, const float* __restrict__ b2,
    float* __restrict__ h,
    const _Float16* __restrict__ w1pn, const float* __restrict__ b1n,
    int do_proj,
    const _Float16* __restrict__ w1dp, const float* __restrict__ db1,
    const _Float16* __restrict__ w2dp, const float* __restrict__ db2,
    const float* __restrict__ dw3, const float* __restrict__ db3,
    float* __restrict__ out, int do_dec)
{
  __shared__ _Float16 Sl[16][136];
  __shared__ _Float16 hl[16][136];
  __shared__ __align__(16) char ubuf[8576];           // dl | (d1 + s2m)
  float    (*dl)[132]  = (float(*)[132])ubuf;         // 16*132*4 = 8448
  _Float16 (*d1)[136]  = (_Float16(*)[136])ubuf;      // 16*136*2 = 4352
  float    (*s2m)[66]  = (float(*)[66])(ubuf + 4352); // 16*66*4  = 4224

  const int tid = threadIdx.x;
  const int w   = __builtin_amdgcn_readfirstlane(tid >> 6);   // wave 0..15
  const int ln  = tid & 63;
  const int q   = ln >> 4;
  const int m   = ln & 15;
  const int n0  = blockIdx.x*16;      // grid = NN/16 = 1250 exact

  // ---- phase 0: edge aggregation, 1 node per wave (r4-identical) ----
  {
    const int n  = n0 + w;
    const int c0 = ln*2;
    const float2v wc0 = *(const float2v*)(w1e +   0 + c0);
    const float2v wc1 = *(const float2v*)(w1e + 128 + c0);
    const float2v wc2 = *(const float2v*)(w1e + 256 + c0);

    half2v uvp = *(const half2v*)(UVc + (size_t)n*256 + c0);
    float2v u; u[0] = (float)uvp[0]; u[1] = (float)uvp[1];

    const int rs = row_start[n], re = row_start[n+1];
    float2v a0 = {0.f,0.f}, a1 = {0.f,0.f}, a2 = {0.f,0.f}, a3 = {0.f,0.f};

    const int nq = (re - rs) >> 2;
    int e = rs;
    for (int qq = 0; qq < nq; ++qq, e += 4){
      const int4 r0 = rec[e+0];
      const int4 r1 = rec[e+1];
      const int4 r2 = rec[e+2];
      const int4 r3 = rec[e+3];
      const half2v v0 = *(const half2v*)(UVc + (size_t)r0.w + 128 + c0);
      const half2v v1 = *(const half2v*)(UVc + (size_t)r1.w + 128 + c0);
      const half2v v2 = *(const half2v*)(UVc + (size_t)r2.w + 128 + c0);
      const half2v v3 = *(const half2v*)(UVc + (size_t)r3.w + 128 + c0);
      a0 += edge_contrib(r0, v0, u, wc0, wc1, wc2);
      a1 += edge_contrib(r1, v1, u, wc0, wc1, wc2);
      a2 += edge_contrib(r2, v2, u, wc0, wc1, wc2);
      a3 += edge_contrib(r3, v3, u, wc0, wc1, wc2);
    }
    if (e < re){
      const int e1 = (e+1 < re) ? e+1 : e;
      const int e2 = (e+2 < re) ? e+2 : e;
      const int4 r0 = rec[e];
      const int4 r1 = rec[e1];
      const int4 r2 = rec[e2];
      const half2v v0 = *(const half2v*)(UVc + (size_t)r0.w + 128 + c0);
      const half2v v1 = *(const half2v*)(UVc + (size_t)r1.w + 128 + c0);
      const half2v v2 = *(const half2v*)(UVc + (size_t)r2.w + 128 + c0);
      a0 += edge_contrib(r0, v0, u, wc0, wc1, wc2);
      if (e+1 < re) a1 += edge_contrib(r1, v1, u, wc0, wc1, wc2);
      if (e+2 < re) a2 += edge_contrib(r2, v2, u, wc0, wc1, wc2);
    }
    float2v a = (a0 + a1) + (a2 + a3);
    const float iv = invd[n];
    half2v outv; outv[0] = (_Float16)(a[0]*iv); outv[1] = (_Float16)(a[1]*iv);
    *(half2v*)&Sl[w][c0] = outv;
  }
  __syncthreads();

  // ---- phase 1: S·W2 -> dl (waves 0-7, one 16x16 col-block each) ----
  if (w < 8){
    floatx4 acc = (floatx4){0.f,0.f,0.f,0.f};
    #pragma unroll
    for (int ks=0; ks<4; ++ks){
      half8 a = *(const half8*)&Sl[m][ks*32 + q*8];
      half8 b = *(const half8*)(w2p + (size_t)(ks*8*64 + ln)*8 + (size_t)w*512);
      acc = __builtin_amdgcn_mfma_f32_16x16x32_f16(a, b, acc, 0,0,0);
    }
    const int c = w*16 + m;
    #pragma unroll
    for (int r=0;r<4;++r) dl[q*4+r][c] = acc[r];
  }
  __syncthreads();

  // ---- phase 2: coalesced h RMW (2 ch/thread); hl fp16 ----
  {
    const int row = w;                  // 2048 elems / 1024 thr = 2 each
    const int col = ln*2;
    const float g = (invd[n0 + row] > 0.f) ? 1.f : 0.f;
    float2 hv = *(const float2*)&h[(size_t)(n0+row)*HD + col];
    float2 bv = *(const float2*)&b2[col];
    float2 dv = *(const float2*)&dl[row][col];
    hv.x += dv.x + g*bv.x;
    hv.y += dv.y + g*bv.y;
    if (!do_dec)
      *(float2*)&h[(size_t)(n0+row)*HD + col] = hv;
    half2v p; p[0] = (_Float16)hv.x; p[1] = (_Float16)hv.y;
    *(half2v*)&hl[row][col] = p;
  }
  __syncthreads();

  // ---- phase 3a: fused proj(l+1) (16 waves, one col-block each) ----
  if (do_proj){
    floatx4 acc = (floatx4){0.f,0.f,0.f,0.f};
    #pragma unroll
    for (int ks=0; ks<4; ++ks){
      half8 a = *(const half8*)&hl[m][ks*32 + q*8];
      half8 b = *(const half8*)(w1pn + (size_t)(ks*16*64 + ln)*8 + (size_t)w*512);
      acc = __builtin_amdgcn_mfma_f32_16x16x32_f16(a, b, acc, 0,0,0);
    }
    const int c = w*16 + m;
    const float bias = (c < 128) ? b1n[c] : 0.f;
    #pragma unroll
    for (int r=0;r<4;++r)
      UVn[(size_t)(n0+q*4+r)*256 + c] = (_Float16)(acc[r] + bias);
  }

  // ---- phase 3b: fused decoder (l==5) ----
  if (do_dec){
    if (w < 8){
      floatx4 acc = (floatx4){0.f,0.f,0.f,0.f};
      #pragma unroll
      for (int ks=0; ks<4; ++ks){
        half8 a = *(const half8*)&hl[m][ks*32 + q*8];
        half8 b = *(const half8*)(w1dp + (size_t)(ks*8*64 + ln)*8 + (size_t)w*512);
        acc = __builtin_amdgcn_mfma_f32_16x16x32_f16(a, b, acc, 0,0,0);
      }
      const int c = w*16 + m;
      const float bv = db1[c];
      #pragma unroll
      for (int r=0;r<4;++r)
        d1[q*4+r][c] = (_Float16)silu_f(acc[r] + bv);
    }
    __syncthreads();

    if (w < 4){
      floatx4 acc = (floatx4){0.f,0.f,0.f,0.f};
      #pragma unroll
      for (int ks=0; ks<4; ++ks){
        half8 a = *(const half8*)&d1[m][ks*32 + q*8];
        half8 b = *(const half8*)(w2dp + (size_t)(ks*4*64 + ln)*8 + (size_t)w*512);
        acc = __builtin_amdgcn_mfma_f32_16x16x32_f16(a, b, acc, 0,0,0);
      }
      const int c = w*16 + m;
      const float bv = db2[c];
      #pragma unroll
      for (int r=0;r<4;++r)
        s2m[q*4+r][c] = silu_f(acc[r] + bv);
    }
    __syncthreads();

    if (tid < 144){
      int i = tid/9, oo = tid%9;
      float a = db3[oo];
      #pragma unroll 8
      for (int k=0;k<64;++k) a += s2m[i][k]*dw3[k*9+oo];
      out[(size_t)(n0+i)*9 + oo] = a;
    }
  }
}

// ---------------- workspace layout (43,119,040 B) ----------------
constexpr size_t OFF_H    = 0;                         // 10,240,000
constexpr size_t OFF_HH   = 10240000;                  //  5,120,000
constexpr size_t OFF_UVA  = 15360000;                  // 10,240,000
constexpr size_t OFF_UVB  = 25600000;                  // 10,240,000
constexpr size_t OFF_INVD = 35840000;                  //     80,000
constexpr size_t OFF_RS   = 35920000;                  //     80,064
constexpr size_t OFF_CUR  = 36000064;                  //     80,000
constexpr size_t OFF_REC  = 36080064;                  //  5,120,000 (int4/edge)
constexpr size_t OFF_RANK = 41200064;                  //  1,280,000 (int/edge)
constexpr size_t OFF_W1P  = 42480064;                  //    393,216
constexpr size_t OFF_W2P  = 42873280;                  //    196,608
constexpr size_t OFF_DW1P = 43069888;                  //     32,768
constexpr size_t OFF_DW2P = 43102656;                  //     16,384
constexpr size_t WS_NEEDED= 43119040;

extern "C" void kernel_launch(void* const* d_in, const int* in_sizes, int n_in,
                              void* d_out, int out_size, void* d_ws, size_t ws_size,
                              hipStream_t stream)
{
  float* out = (float*)d_out;
  const int nout_blk = (out_size + 255)/256;

  static const int EXP_SIZES[17] = {280000,640000,960000,1792,128,16384,128,
                                    198912,768,98304,768,16384,128,8192,64,576,9};
  if (n_in != 17){
    sentinel_kernel<<<nout_blk, 256, 0, stream>>>(out, out_size, 2.0e7f + (float)n_in*1.0e3f);
    return;
  }
  for (int i = 0; i < 17; ++i){
    if (in_sizes[i] != EXP_SIZES[i]){
      int sz = in_sizes[i] < 99999 ? in_sizes[i] : 99999;
      sentinel_kernel<<<nout_blk, 256, 0, stream>>>(out, out_size,
          1.0e7f + (float)i*1.0e5f + (float)sz);
      return;
    }
  }
  if (ws_size < WS_NEEDED){
    sentinel_kernel<<<nout_blk, 256, 0, stream>>>(out, out_size, 1.0e6f);
    return;
  }

  const float* x       = (const float*)d_in[0];
  const int*   ei      = (const int*)  d_in[1];
  const float* eattr   = (const float*)d_in[2];
  const float* enc_w1  = (const float*)d_in[3];
  const float* enc_b1  = (const float*)d_in[4];
  const float* enc_w2  = (const float*)d_in[5];
  const float* enc_b2  = (const float*)d_in[6];
  const float* conv_w1 = (const float*)d_in[7];
  const float* conv_b1 = (const float*)d_in[8];
  const float* conv_w2 = (const float*)d_in[9];
  const float* conv_b2 = (const float*)d_in[10];
  const float* dec_w1  = (const float*)d_in[11];
  const float* dec_b1  = (const float*)d_in[12];
  const float* dec_w2  = (const float*)d_in[13];
  const float* dec_b2  = (const float*)d_in[14];
  const float* dec_w3  = (const float*)d_in[15];
  const float* dec_b3  = (const float*)d_in[16];

  char* ws = (char*)d_ws;
  float*    h     = (float*)   (ws + OFF_H);
  _Float16* hh    = (_Float16*)(ws + OFF_HH);
  _Float16* UVa   = (_Float16*)(ws + OFF_UVA);
  _Float16* UVb   = (_Float16*)(ws + OFF_UVB);
  float*    invd  = (float*)   (ws + OFF_INVD);
  int*      rstart= (int*)     (ws + OFF_RS);
  int*      cur   = (int*)     (ws + OFF_CUR);
  int4*     rec   = (int4*)    (ws + OFF_REC);
  int*      rank  = (int*)     (ws + OFF_RANK);
  _Float16* w1p   = (_Float16*)(ws + OFF_W1P);
  _Float16* w2p   = (_Float16*)(ws + OFF_W2P);
  _Float16* w1dp  = (_Float16*)(ws + OFF_DW1P);
  _Float16* w2dp  = (_Float16*)(ws + OFF_DW2P);

  pack_all_kernel<<<1327, 256, 0, stream>>>(conv_w1, conv_w2, dec_w1, dec_w2,
                                            w1p, w2p, w1dp, w2dp, cur);
  count_kernel<<<EE/256, 256, 0, stream>>>(ei, cur, rank);
  scan_kernel<<<1, 1024, 0, stream>>>(cur, rstart, invd);
  scatter_encoder_kernel<<<3750, 128, 0, stream>>>(ei, eattr, rstart, rank, rec,
                                                   x, enc_w1, enc_b1, enc_w2, enc_b2,
                                                   h, hh);
  proj_kernel<<<NN/16, 256, 0, stream>>>(hh, w1p, conv_b1, UVa);   // layer 0 proj
  for (int l=0; l<6; ++l){
    _Float16* UVc = (l & 1) ? UVb : UVa;
    _Float16* UVn = (l & 1) ? UVa : UVb;
    const int lp = (l < 5) ? l+1 : 0;   // dummy valid ptrs for last layer
    layer_kernel<<<NN/16, 1024, 0, stream>>>(UVc, UVn, rstart, rec,
                                             conv_w1 + (size_t)l*33152 + 32768,
                                             invd,
                                             w2p + (size_t)l*16384,
                                             conv_b2 + (size_t)l*128,
                                             h,
                                             w1p + (size_t)lp*32768,
                                             conv_b1 + (size_t)lp*128,
                                             (l < 5) ? 1 : 0,
                                             w1dp, dec_b1, w2dp, dec_b2,
                                             dec_w3, dec_b3, out,
                                             (l == 5) ? 1 : 0);
  }
}